// Round 10
// baseline (210.237 us; speedup 1.0000x reference)
//
#include <hip/hip_runtime.h>

typedef unsigned short u16;
typedef __attribute__((ext_vector_type(8))) _Float16 f16x8;
typedef __attribute__((ext_vector_type(4))) float f32x4;

#define S 4096
#define E 512
#define NH 8
#define NG 16         // kb-groups per row (16 groups of 4 blocks = 256 cols/group)
#define KBG 4         // 64-col k-blocks per group
#define QPREMUL 0.18033688011f  // 0.125 * log2(e): scores in log2 domain -> exp2f

__device__ __forceinline__ u16 f2h(float f) {
  union { _Float16 h; u16 u; } v; v.h = (_Float16)f; return v.u;
}

// Fused prep: blocks [0,1024) repack x -> XF (A-fragment fp16);
// blocks [1024,1536) repack the four 512x512 weights -> B-fragment fp16.
__global__ void prep_kernel(const float* __restrict__ x,
                            const float* __restrict__ Wq, const float* __restrict__ Wk,
                            const float* __restrict__ Wv, const float* __restrict__ Wo,
                            u16* __restrict__ XF,
                            u16* __restrict__ wqF, u16* __restrict__ wkF,
                            u16* __restrict__ wvF, u16* __restrict__ woF) {
  const int bid = blockIdx.x;
  if (bid < 1024) {
    int o = bid * 256 + threadIdx.x;  // 0..S*E/8-1
    int l = o & 63, ks = (o >> 6) & 15, w = (o >> 10) & 3, mb = o >> 12;
    int row = mb * 64 + w * 16 + (l & 15);
    int col = ks * 32 + ((l >> 4) << 3);
    const float4 f0 = *(const float4*)&x[row * 512 + col];
    const float4 f1 = *(const float4*)&x[row * 512 + col + 4];
    f16x8 v;
    v[0] = (_Float16)f0.x; v[1] = (_Float16)f0.y; v[2] = (_Float16)f0.z; v[3] = (_Float16)f0.w;
    v[4] = (_Float16)f1.x; v[5] = (_Float16)f1.y; v[6] = (_Float16)f1.z; v[7] = (_Float16)f1.w;
    *(f16x8*)&XF[o * 8] = v;
  } else {
    int which = (bid - 1024) >> 7;
    int o = ((bid - 1024) & 127) * 256 + threadIdx.x;  // 0..512*512/8-1
    int l = o & 63, ks = (o >> 6) & 15, ct = (o >> 10) & 3, nb = o >> 12;
    int n = nb * 64 + ct * 16 + (l & 15);
    int k0 = ks * 32 + ((l >> 4) << 3);
    const float* W = which == 0 ? Wq : which == 1 ? Wk : which == 2 ? Wv : Wo;
    u16* dst = which == 0 ? wqF : which == 1 ? wkF : which == 2 ? wvF : woF;
    f16x8 v;
#pragma unroll
    for (int j = 0; j < 8; ++j) v[j] = (_Float16)W[(k0 + j) * 512 + n];
    *(f16x8*)&dst[o * 8] = v;
  }
}

// Fused Q/K/V projection. blockIdx.z: 0=Q (frag out, premul), 1=K (frag out),
// 2=V (V-fragment out via cross-wave LDS transpose).
__global__ __launch_bounds__(256) void qkv_kernel(
    const u16* __restrict__ XF,
    const u16* __restrict__ wqF, const u16* __restrict__ wkF, const u16* __restrict__ wvF,
    const float* __restrict__ bq, const float* __restrict__ bk, const float* __restrict__ bv,
    u16* __restrict__ QF, u16* __restrict__ KF, u16* __restrict__ VF) {
  const int mb = blockIdx.x, nb = blockIdx.y, z = blockIdx.z;
  const int w = threadIdx.x >> 6, l = threadIdx.x & 63;
  const int lr = l & 15, hi4 = l >> 4;
  const u16* BF = z == 0 ? wqF : z == 1 ? wkF : wvF;
  const float* bias = z == 0 ? bq : z == 1 ? bk : bv;

  f32x4 acc[4] = {{0.f,0.f,0.f,0.f},{0.f,0.f,0.f,0.f},{0.f,0.f,0.f,0.f},{0.f,0.f,0.f,0.f}};
  const u16* abase = XF + (size_t)((mb * 4 + w) * 16) * 512 + l * 8;
  const u16* bbase = BF + (size_t)(nb * 64) * 512 + l * 8;
#pragma unroll
  for (int ks = 0; ks < 16; ++ks) {
    f16x8 ah = *(const f16x8*)(abase + ks * 512);
#pragma unroll
    for (int ct = 0; ct < 4; ++ct) {
      f16x8 bh = *(const f16x8*)(bbase + (ct * 16 + ks) * 512);
      acc[ct] = __builtin_amdgcn_mfma_f32_16x16x32_f16(ah, bh, acc[ct], 0, 0, 0);
    }
  }

  __shared__ __align__(16) char smraw[64 * 69 * 4];
  if (z < 2) {
    float (*sm)[16][68] = (float (*)[16][68])smraw;  // per-wave [4][16][68]
    const float premul = z == 0 ? QPREMUL : 1.0f;
#pragma unroll
    for (int ct = 0; ct < 4; ++ct) {
      float bia = bias[nb * 64 + ct * 16 + lr];
#pragma unroll
      for (int r = 0; r < 4; ++r)
        sm[w][hi4 * 4 + r][ct * 16 + lr] = (acc[ct][r] + bia) * premul;
    }
    asm volatile("s_waitcnt lgkmcnt(0)" ::: "memory");
    u16* dst = z == 0 ? QF : KF;
#pragma unroll
    for (int half = 0; half < 2; ++half) {
      const float* src = &sm[w][lr][half * 32 + hi4 * 8];
      const f32x4 f0 = *(const f32x4*)src;
      const f32x4 f1 = *(const f32x4*)(src + 4);
      f16x8 o8;
      o8[0] = (_Float16)f0[0]; o8[1] = (_Float16)f0[1];
      o8[2] = (_Float16)f0[2]; o8[3] = (_Float16)f0[3];
      o8[4] = (_Float16)f1[0]; o8[5] = (_Float16)f1[1];
      o8[6] = (_Float16)f1[2]; o8[7] = (_Float16)f1[3];
      *(f16x8*)&dst[(size_t)(nb * 64 + mb) * 4096 + w * 1024 + half * 512 + l * 8] = o8;
    }
  } else {
    float (*sm)[69] = (float (*)[69])smraw;  // whole-WG [64][69]
#pragma unroll
    for (int ct = 0; ct < 4; ++ct) {
      float bia = bias[nb * 64 + ct * 16 + lr];
#pragma unroll
      for (int r = 0; r < 4; ++r)
        sm[w * 16 + hi4 * 4 + r][ct * 16 + lr] = acc[ct][r] + bia;
    }
    __syncthreads();
#pragma unroll
    for (int hh = 0; hh < 2; ++hh) {
      f16x8 v;
#pragma unroll
      for (int j = 0; j < 8; ++j)
        v[j] = (_Float16)sm[hh * 32 + hi4 * 8 + j][w * 16 + lr];
      *(f16x8*)&VF[(size_t)(nb * 64 + mb) * 4096 + w * 1024 + hh * 512 + l * 8] = v;
    }
  }
}

// pass 1: pure compute — partial sum-of-exp2 per row per 256-col group.
// Non-causal WGs exit immediately. Q pre-scaled by 0.125*log2(e).
__global__ __launch_bounds__(256) void ksum_kernel(
    const u16* __restrict__ QF, const u16* __restrict__ KF,
    float* __restrict__ ws_l) {
  const int gx = blockIdx.x;
  const int h = blockIdx.y;
  const int qb = 63 - (int)blockIdx.z;  // heavy rows dispatched first
  const int kb0 = gx * KBG;
  if (kb0 > qb) return;
  const int w = threadIdx.x >> 6, l = threadIdx.x & 63;
  const int lr = l & 15, hi4 = l >> 4;
  const int q0 = qb * 64;

  const int qbase = (h * 64 + qb) * 4096 + w * 1024 + l * 8;
  f16x8 q0f = *(const f16x8*)&QF[qbase];
  f16x8 q1f = *(const f16x8*)&QF[qbase + 512];

  const int rowg = q0 + w * 16 + hi4 * 4;
  float acc[4] = {0.f, 0.f, 0.f, 0.f};

  const int kbend = min(kb0 + KBG, qb + 1);
  for (int kb = kb0; kb < kbend; ++kb) {
    const int kbase = (h * 64 + kb) * 4096 + l * 8;
#pragma unroll
    for (int ct = 0; ct < 4; ++ct) {
      f16x8 k0 = *(const f16x8*)&KF[kbase + ct * 1024];
      f16x8 k1 = *(const f16x8*)&KF[kbase + ct * 1024 + 512];
      f32x4 a = {0.f, 0.f, 0.f, 0.f};
      a = __builtin_amdgcn_mfma_f32_16x16x32_f16(q0f, k0, a, 0, 0, 0);
      a = __builtin_amdgcn_mfma_f32_16x16x32_f16(q1f, k1, a, 0, 0, 0);
      if (kb != qb) {
#pragma unroll
        for (int r = 0; r < 4; ++r) acc[r] += exp2f(a[r]);
      } else {
        const int colb = kb * 64 + ct * 16 + lr;
#pragma unroll
        for (int r = 0; r < 4; ++r)
          acc[r] += (colb <= rowg + r) ? exp2f(a[r]) : 0.f;
      }
    }
  }
#pragma unroll
  for (int r = 0; r < 4; ++r) {
    float v = acc[r];
#pragma unroll
    for (int off = 1; off < 16; off <<= 1) v += __shfl_xor(v, off);
    if (lr == 0) ws_l[(size_t)(h * NG + gx) * S + rowg + r] = v;
  }
}

// pass 2: ALL attw stores live here (uniform 64KB/WG). Causal blocks:
// recompute scores, normalize (invl summed inline), store P, partial PV.
// Non-causal WGs / tail blocks: nontemporal zero-fill.
__global__ __launch_bounds__(256) void kwts_kernel(
    const u16* __restrict__ QF, const u16* __restrict__ KF,
    const u16* __restrict__ VF, const float* __restrict__ ws_l,
    float* __restrict__ attw, u16* __restrict__ ppv) {
  __shared__ __align__(16) float sm[4][16][68];
  const int gx = blockIdx.x;
  const int h = blockIdx.y;
  const int qb = 63 - (int)blockIdx.z;
  const int kb0 = gx * KBG;
  const int t = threadIdx.x;
  const int q0 = qb * 64;

  if (kb0 > qb) {
    // fully-above-diagonal 64x256 strip: pure zero-fill
    const size_t base = (size_t)(h * S + q0) * S + gx * 256;
    const f32x4 z = {0.f, 0.f, 0.f, 0.f};
#pragma unroll
    for (int j = 0; j < 16; ++j) {
      int idx = j * 256 + t;
      int row = idx >> 6, c4 = idx & 63;
      __builtin_nontemporal_store(z, (f32x4*)&attw[base + (size_t)row * S + c4 * 4]);
    }
    return;
  }

  const int w = t >> 6, l = t & 63;
  const int lr = l & 15, hi4 = l >> 4, lk = hi4 * 8;
  const int rowg = q0 + w * 16 + hi4 * 4;
  const int kbend_c = min(kb0 + KBG, qb + 1);

  const int qbase = (h * 64 + qb) * 4096 + w * 1024 + l * 8;
  f16x8 q0f = *(const f16x8*)&QF[qbase];
  f16x8 q1f = *(const f16x8*)&QF[qbase + 512];

  // inline invl: sum group partials for this WG's rows
  const int ngc = (qb >> 2) + 1;
  float iv[4];
#pragma unroll
  for (int r = 0; r < 4; ++r) {
    float ssum = 0.f;
    for (int c = 0; c < ngc; ++c) ssum += ws_l[(size_t)(h * NG + c) * S + rowg + r];
    iv[r] = 1.0f / ssum;
  }

  f32x4 o[4] = {{0.f,0.f,0.f,0.f},{0.f,0.f,0.f,0.f},{0.f,0.f,0.f,0.f},{0.f,0.f,0.f,0.f}};

  for (int kb = kb0; kb < kb0 + KBG; ++kb) {
    if (kb < kbend_c) {
      const int kbase = (h * 64 + kb) * 4096 + l * 8;
#pragma unroll
      for (int ct = 0; ct < 4; ++ct) {
        f16x8 k0 = *(const f16x8*)&KF[kbase + ct * 1024];
        f16x8 k1 = *(const f16x8*)&KF[kbase + ct * 1024 + 512];
        f32x4 a = {0.f, 0.f, 0.f, 0.f};
        a = __builtin_amdgcn_mfma_f32_16x16x32_f16(q0f, k0, a, 0, 0, 0);
        a = __builtin_amdgcn_mfma_f32_16x16x32_f16(q1f, k1, a, 0, 0, 0);
        if (kb != qb) {
#pragma unroll
          for (int r = 0; r < 4; ++r)
            sm[w][hi4 * 4 + r][ct * 16 + lr] = exp2f(a[r]) * iv[r];
        } else {
          const int colb = kb * 64 + ct * 16 + lr;
#pragma unroll
          for (int r = 0; r < 4; ++r)
            sm[w][hi4 * 4 + r][ct * 16 + lr] =
                (colb <= rowg + r) ? exp2f(a[r]) * iv[r] : 0.f;
        }
      }
      asm volatile("s_waitcnt lgkmcnt(0)" ::: "memory");
#pragma unroll
      for (int j = 0; j < 4; ++j) {
        const int row16 = hi4 + 4 * j;
        const f32x4 pv4 = *(const f32x4*)&sm[w][row16][lr * 4];
        __builtin_nontemporal_store(
            pv4, (f32x4*)&attw[(size_t)(h * S + q0 + w * 16 + row16) * S + kb * 64 + lr * 4]);
      }
#pragma unroll
      for (int ks = 0; ks < 2; ++ks) {
        const f32x4 f0 = *(const f32x4*)&sm[w][lr][ks * 32 + lk];
        const f32x4 f1 = *(const f32x4*)&sm[w][lr][ks * 32 + lk + 4];
        f16x8 pa;
        pa[0] = (_Float16)f0[0]; pa[1] = (_Float16)f0[1];
        pa[2] = (_Float16)f0[2]; pa[3] = (_Float16)f0[3];
        pa[4] = (_Float16)f1[0]; pa[5] = (_Float16)f1[1];
        pa[6] = (_Float16)f1[2]; pa[7] = (_Float16)f1[3];
        const int vbase = (h * 64 + kb) * 4096 + ks * 512 + l * 8;
#pragma unroll
        for (int ct2 = 0; ct2 < 4; ++ct2) {
          f16x8 bv = *(const f16x8*)&VF[vbase + ct2 * 1024];
          o[ct2] = __builtin_amdgcn_mfma_f32_16x16x32_f16(pa, bv, o[ct2], 0, 0, 0);
        }
      }
      asm volatile("" ::: "memory");
    } else {
      const f32x4 z = {0.f, 0.f, 0.f, 0.f};
#pragma unroll
      for (int j = 0; j < 4; ++j) {
        __builtin_nontemporal_store(
            z, (f32x4*)&attw[(size_t)(h * S + q0 + w * 16 + hi4 + 4 * j) * S + kb * 64 + lr * 4]);
      }
    }
  }

#pragma unroll
  for (int ct2 = 0; ct2 < 4; ++ct2)
#pragma unroll
    for (int r = 0; r < 4; ++r)
      ppv[((size_t)(h * NG + gx) * S + rowg + r) * 64 + ct2 * 16 + lr] = f2h(o[ct2][r]);
}

// reduce PV partials (fp16) over groups -> AO in A-fragment order (fp16)
__global__ void pvred_kernel(const u16* __restrict__ ppv, u16* __restrict__ AOF) {
  int t = blockIdx.x * blockDim.x + threadIdx.x;  // S*E/8 threads
  int r = t >> 6, c8 = t & 63;
  int c = c8 * 8;
  int h = c >> 6, dd = c & 63;
  int ng = (r >> 8) + 1;  // groups with causal content (256 cols each)
  float s[8] = {0.f, 0.f, 0.f, 0.f, 0.f, 0.f, 0.f, 0.f};
  for (int g = 0; g < ng; ++g) {
    const f16x8 v = *(const f16x8*)&ppv[((size_t)(h * NG + g) * S + r) * 64 + dd];
#pragma unroll
    for (int j = 0; j < 8; ++j) s[j] += (float)v[j];
  }
  f16x8 o;
#pragma unroll
  for (int j = 0; j < 8; ++j) o[j] = (_Float16)s[j];
  int mb = r >> 6, w = (r >> 4) & 3, ll = r & 15;
  int ks = c >> 5, lhi = (c >> 3) & 3;
  int l = lhi * 16 + ll;
  *(f16x8*)&AOF[(size_t)(((mb * 4 + w) * 16 + ks)) * 512 + l * 8] = o;
}

// final O projection: fragment-order A,B -> fp32 row-major out
__global__ __launch_bounds__(256) void gemm_o_kernel(
    const u16* __restrict__ AF, const u16* __restrict__ BF,
    const float* __restrict__ bias, float* __restrict__ outf) {
  const int mb = blockIdx.x, nb = blockIdx.y;
  const int w = threadIdx.x >> 6, l = threadIdx.x & 63;
  const int lr = l & 15, hi4 = l >> 4;

  f32x4 acc[4] = {{0.f,0.f,0.f,0.f},{0.f,0.f,0.f,0.f},{0.f,0.f,0.f,0.f},{0.f,0.f,0.f,0.f}};
  const u16* abase = AF + (size_t)((mb * 4 + w) * 16) * 512 + l * 8;
  const u16* bbase = BF + (size_t)(nb * 64) * 512 + l * 8;
#pragma unroll
  for (int ks = 0; ks < 16; ++ks) {
    f16x8 ah = *(const f16x8*)(abase + ks * 512);
#pragma unroll
    for (int ct = 0; ct < 4; ++ct) {
      f16x8 bh = *(const f16x8*)(bbase + (ct * 16 + ks) * 512);
      acc[ct] = __builtin_amdgcn_mfma_f32_16x16x32_f16(ah, bh, acc[ct], 0, 0, 0);
    }
  }
  const int rb = mb * 64 + w * 16 + hi4 * 4;
#pragma unroll
  for (int ct = 0; ct < 4; ++ct) {
    int n = nb * 64 + ct * 16 + lr;
    float bia = bias[n];
#pragma unroll
    for (int r = 0; r < 4; ++r)
      outf[(rb + r) * E + n] = acc[ct][r] + bia;
  }
}

extern "C" void kernel_launch(void* const* d_in, const int* in_sizes, int n_in,
                              void* d_out, int out_size, void* d_ws, size_t ws_size,
                              hipStream_t stream) {
  const float* x  = (const float*)d_in[0];
  const float* Wq = (const float*)d_in[2];
  const float* bq = (const float*)d_in[3];
  const float* Wk = (const float*)d_in[4];
  const float* bk = (const float*)d_in[5];
  const float* Wv = (const float*)d_in[6];
  const float* bv = (const float*)d_in[7];
  const float* Wo = (const float*)d_in[8];
  const float* bo = (const float*)d_in[9];

  u16* p = (u16*)d_ws;
  u16* XF  = p; p += S * E;
  u16* wqF = p; p += 512 * 512;
  u16* wkF = p; p += 512 * 512;
  u16* wvF = p; p += 512 * 512;
  u16* woF = p; p += 512 * 512;
  u16* QF  = p; p += S * E;
  u16* KF  = p; p += S * E;
  u16* VF  = p; p += S * E;
  u16* AOF = p; p += S * E;
  size_t ofs = ((size_t)((char*)p - (char*)d_ws) + 15) & ~(size_t)15;
  float* ws_l = (float*)((char*)d_ws + ofs);               // NH*NG*S
  u16*   ppv  = (u16*)(ws_l + (size_t)NH * NG * S);        // NH*NG*S*64 fp16
  char* wend = (char*)(ppv + (size_t)NH * NG * S * 64);

  size_t needed = (size_t)(wend - (char*)d_ws);
  if (ws_size < needed) return;

  float* out  = (float*)d_out;
  float* attw = out + (size_t)S * E;

  prep_kernel<<<1536, 256, 0, stream>>>(x, Wq, Wk, Wv, Wo, XF, wqF, wkF, wvF, woF);

  qkv_kernel<<<dim3(S / 64, E / 64, 3), 256, 0, stream>>>(
      XF, wqF, wkF, wvF, bq, bk, bv, QF, KF, VF);

  ksum_kernel<<<dim3(NG, NH, S / 64), 256, 0, stream>>>(QF, KF, ws_l);
  kwts_kernel<<<dim3(NG, NH, S / 64), 256, 0, stream>>>(QF, KF, VF, ws_l, attw, ppv);
  pvred_kernel<<<(S * E / 8) / 256, 256, 0, stream>>>(ppv, AOF);

  gemm_o_kernel<<<dim3(S / 64, E / 64), 256, 0, stream>>>(AOF, woF, bo, out);
}

// Round 11
// 191.799 us; speedup vs baseline: 1.0961x; 1.0961x over previous
//
#include <hip/hip_runtime.h>

typedef unsigned short u16;
typedef __attribute__((ext_vector_type(8))) _Float16 f16x8;
typedef __attribute__((ext_vector_type(4))) float f32x4;

#define S 4096
#define E 512
#define NH 8
#define NG 8          // kb-groups per row (8 blocks of 64 cols each = 512 cols/group)
#define KBG 8         // 64-col k-blocks per group
#define QPREMUL 0.18033688011f  // 0.125 * log2(e): scores in log2 domain -> exp2f

__device__ __forceinline__ u16 f2h(float f) {
  union { _Float16 h; u16 u; } v; v.h = (_Float16)f; return v.u;
}

// x (fp32 row-major [S][512]) -> A-fragment fp16
__global__ void xfrag_kernel(const float* __restrict__ x, u16* __restrict__ XF) {
  int o = blockIdx.x * blockDim.x + threadIdx.x;  // 0..S*E/8-1
  int l = o & 63, ks = (o >> 6) & 15, w = (o >> 10) & 3, mb = o >> 12;
  int row = mb * 64 + w * 16 + (l & 15);
  int col = ks * 32 + ((l >> 4) << 3);
  const float4 f0 = *(const float4*)&x[row * 512 + col];
  const float4 f1 = *(const float4*)&x[row * 512 + col + 4];
  f16x8 v;
  v[0] = (_Float16)f0.x; v[1] = (_Float16)f0.y; v[2] = (_Float16)f0.z; v[3] = (_Float16)f0.w;
  v[4] = (_Float16)f1.x; v[5] = (_Float16)f1.y; v[6] = (_Float16)f1.z; v[7] = (_Float16)f1.w;
  *(f16x8*)&XF[o * 8] = v;
}

// W (fp32 [k][n]) -> B-fragment fp16
__global__ void wfrag_kernel(const float* __restrict__ Wq, const float* __restrict__ Wk,
                             const float* __restrict__ Wv, const float* __restrict__ Wo,
                             u16* __restrict__ wqF, u16* __restrict__ wkF,
                             u16* __restrict__ wvF, u16* __restrict__ woF) {
  int o = blockIdx.x * blockDim.x + threadIdx.x;  // 0..512*512/8-1
  int which = blockIdx.y;
  int l = o & 63, ks = (o >> 6) & 15, ct = (o >> 10) & 3, nb = o >> 12;
  int n = nb * 64 + ct * 16 + (l & 15);
  int k0 = ks * 32 + ((l >> 4) << 3);
  const float* W = which == 0 ? Wq : which == 1 ? Wk : which == 2 ? Wv : Wo;
  u16* dst = which == 0 ? wqF : which == 1 ? wkF : which == 2 ? wvF : woF;
  f16x8 v;
#pragma unroll
  for (int j = 0; j < 8; ++j) v[j] = (_Float16)W[(k0 + j) * 512 + n];
  *(f16x8*)&dst[o * 8] = v;
}

// Fused Q/K/V projection. blockIdx.z: 0=Q (frag out, premul), 1=K (frag out),
// 2=V (V-fragment out via cross-wave LDS transpose).
__global__ __launch_bounds__(256) void qkv_kernel(
    const u16* __restrict__ XF,
    const u16* __restrict__ wqF, const u16* __restrict__ wkF, const u16* __restrict__ wvF,
    const float* __restrict__ bq, const float* __restrict__ bk, const float* __restrict__ bv,
    u16* __restrict__ QF, u16* __restrict__ KF, u16* __restrict__ VF) {
  const int mb = blockIdx.x, nb = blockIdx.y, z = blockIdx.z;
  const int w = threadIdx.x >> 6, l = threadIdx.x & 63;
  const int lr = l & 15, hi4 = l >> 4;
  const u16* BF = z == 0 ? wqF : z == 1 ? wkF : wvF;
  const float* bias = z == 0 ? bq : z == 1 ? bk : bv;

  f32x4 acc[4] = {{0.f,0.f,0.f,0.f},{0.f,0.f,0.f,0.f},{0.f,0.f,0.f,0.f},{0.f,0.f,0.f,0.f}};
  const u16* abase = XF + (size_t)((mb * 4 + w) * 16) * 512 + l * 8;
  const u16* bbase = BF + (size_t)(nb * 64) * 512 + l * 8;
#pragma unroll
  for (int ks = 0; ks < 16; ++ks) {
    f16x8 ah = *(const f16x8*)(abase + ks * 512);
#pragma unroll
    for (int ct = 0; ct < 4; ++ct) {
      f16x8 bh = *(const f16x8*)(bbase + (ct * 16 + ks) * 512);
      acc[ct] = __builtin_amdgcn_mfma_f32_16x16x32_f16(ah, bh, acc[ct], 0, 0, 0);
    }
  }

  __shared__ __align__(16) char smraw[64 * 69 * 4];
  if (z < 2) {
    float (*sm)[16][68] = (float (*)[16][68])smraw;  // per-wave [4][16][68]
    const float premul = z == 0 ? QPREMUL : 1.0f;
#pragma unroll
    for (int ct = 0; ct < 4; ++ct) {
      float bia = bias[nb * 64 + ct * 16 + lr];
#pragma unroll
      for (int r = 0; r < 4; ++r)
        sm[w][hi4 * 4 + r][ct * 16 + lr] = (acc[ct][r] + bia) * premul;
    }
    asm volatile("s_waitcnt lgkmcnt(0)" ::: "memory");
    u16* dst = z == 0 ? QF : KF;
#pragma unroll
    for (int half = 0; half < 2; ++half) {
      const float* src = &sm[w][lr][half * 32 + hi4 * 8];
      const f32x4 f0 = *(const f32x4*)src;
      const f32x4 f1 = *(const f32x4*)(src + 4);
      f16x8 o8;
      o8[0] = (_Float16)f0[0]; o8[1] = (_Float16)f0[1];
      o8[2] = (_Float16)f0[2]; o8[3] = (_Float16)f0[3];
      o8[4] = (_Float16)f1[0]; o8[5] = (_Float16)f1[1];
      o8[6] = (_Float16)f1[2]; o8[7] = (_Float16)f1[3];
      *(f16x8*)&dst[(size_t)(nb * 64 + mb) * 4096 + w * 1024 + half * 512 + l * 8] = o8;
    }
  } else {
    float (*sm)[69] = (float (*)[69])smraw;  // whole-WG [64][69]
#pragma unroll
    for (int ct = 0; ct < 4; ++ct) {
      float bia = bias[nb * 64 + ct * 16 + lr];
#pragma unroll
      for (int r = 0; r < 4; ++r)
        sm[w * 16 + hi4 * 4 + r][ct * 16 + lr] = acc[ct][r] + bia;
    }
    __syncthreads();
#pragma unroll
    for (int hh = 0; hh < 2; ++hh) {
      f16x8 v;
#pragma unroll
      for (int j = 0; j < 8; ++j)
        v[j] = (_Float16)sm[hh * 32 + hi4 * 8 + j][w * 16 + lr];
      *(f16x8*)&VF[(size_t)(nb * 64 + mb) * 4096 + w * 1024 + hh * 512 + l * 8] = v;
    }
  }
}

// pass 1: pure compute — partial sum-of-exp2 per row per 512-col group.
// Non-causal WGs exit immediately. Q pre-scaled by 0.125*log2(e).
__global__ __launch_bounds__(256) void ksum_kernel(
    const u16* __restrict__ QF, const u16* __restrict__ KF,
    float* __restrict__ ws_l) {
  const int gx = blockIdx.x;
  const int h = blockIdx.y;
  const int qb = 63 - (int)blockIdx.z;  // heavy rows dispatched first
  const int kb0 = gx * KBG;
  if (kb0 > qb) return;
  const int w = threadIdx.x >> 6, l = threadIdx.x & 63;
  const int lr = l & 15, hi4 = l >> 4;
  const int q0 = qb * 64;

  const int qbase = (h * 64 + qb) * 4096 + w * 1024 + l * 8;
  f16x8 q0f = *(const f16x8*)&QF[qbase];
  f16x8 q1f = *(const f16x8*)&QF[qbase + 512];

  const int rowg = q0 + w * 16 + hi4 * 4;
  float acc[4] = {0.f, 0.f, 0.f, 0.f};

  const int kbend = min(kb0 + KBG, qb + 1);
  for (int kb = kb0; kb < kbend; ++kb) {
    const int kbase = (h * 64 + kb) * 4096 + l * 8;
#pragma unroll
    for (int ct = 0; ct < 4; ++ct) {
      f16x8 k0 = *(const f16x8*)&KF[kbase + ct * 1024];
      f16x8 k1 = *(const f16x8*)&KF[kbase + ct * 1024 + 512];
      f32x4 a = {0.f, 0.f, 0.f, 0.f};
      a = __builtin_amdgcn_mfma_f32_16x16x32_f16(q0f, k0, a, 0, 0, 0);
      a = __builtin_amdgcn_mfma_f32_16x16x32_f16(q1f, k1, a, 0, 0, 0);
      if (kb != qb) {
#pragma unroll
        for (int r = 0; r < 4; ++r) acc[r] += exp2f(a[r]);
      } else {
        const int colb = kb * 64 + ct * 16 + lr;
#pragma unroll
        for (int r = 0; r < 4; ++r)
          acc[r] += (colb <= rowg + r) ? exp2f(a[r]) : 0.f;
      }
    }
  }
#pragma unroll
  for (int r = 0; r < 4; ++r) {
    float v = acc[r];
#pragma unroll
    for (int off = 1; off < 16; off <<= 1) v += __shfl_xor(v, off);
    if (lr == 0) ws_l[(size_t)(h * NG + gx) * S + rowg + r] = v;
  }
}

// pass 2: ALL attw stores live here (uniform 128KB/WG). Causal blocks:
// recompute scores, normalize (invl computed inline from ws_l), store P,
// partial PV. Non-causal WGs / tail blocks: nontemporal zero-fill.
__global__ __launch_bounds__(256) void kwts_kernel(
    const u16* __restrict__ QF, const u16* __restrict__ KF,
    const u16* __restrict__ VF, const float* __restrict__ ws_l,
    float* __restrict__ attw, u16* __restrict__ ppv) {
  __shared__ __align__(16) float sm[4][16][68];
  const int gx = blockIdx.x;
  const int h = blockIdx.y;
  const int qb = 63 - (int)blockIdx.z;
  const int kb0 = gx * KBG;
  const int t = threadIdx.x;
  const int q0 = qb * 64;

  if (kb0 > qb) {
    // fully-above-diagonal 64x512 strip: pure zero-fill
    const size_t base = (size_t)(h * S + q0) * S + gx * 512;
    const f32x4 z = {0.f, 0.f, 0.f, 0.f};
#pragma unroll
    for (int j = 0; j < 32; ++j) {
      int idx = j * 256 + t;
      int row = idx >> 7, c4 = idx & 127;
      __builtin_nontemporal_store(z, (f32x4*)&attw[base + (size_t)row * S + c4 * 4]);
    }
    return;
  }

  const int w = t >> 6, l = t & 63;
  const int lr = l & 15, hi4 = l >> 4, lk = hi4 * 8;
  const int rowg = q0 + w * 16 + hi4 * 4;
  const int kbend_c = min(kb0 + KBG, qb + 1);

  const int qbase = (h * 64 + qb) * 4096 + w * 1024 + l * 8;
  f16x8 q0f = *(const f16x8*)&QF[qbase];
  f16x8 q1f = *(const f16x8*)&QF[qbase + 512];

  // inline invl: sum group partials for this WG's rows
  const int ngc = (qb >> 3) + 1;
  float iv[4];
#pragma unroll
  for (int r = 0; r < 4; ++r) {
    float ssum = 0.f;
    for (int c = 0; c < ngc; ++c) ssum += ws_l[(size_t)(h * NG + c) * S + rowg + r];
    iv[r] = 1.0f / ssum;
  }

  f32x4 o[4] = {{0.f,0.f,0.f,0.f},{0.f,0.f,0.f,0.f},{0.f,0.f,0.f,0.f},{0.f,0.f,0.f,0.f}};

  for (int kb = kb0; kb < kb0 + KBG; ++kb) {
    if (kb < kbend_c) {
      const int kbase = (h * 64 + kb) * 4096 + l * 8;
#pragma unroll
      for (int ct = 0; ct < 4; ++ct) {
        f16x8 k0 = *(const f16x8*)&KF[kbase + ct * 1024];
        f16x8 k1 = *(const f16x8*)&KF[kbase + ct * 1024 + 512];
        f32x4 a = {0.f, 0.f, 0.f, 0.f};
        a = __builtin_amdgcn_mfma_f32_16x16x32_f16(q0f, k0, a, 0, 0, 0);
        a = __builtin_amdgcn_mfma_f32_16x16x32_f16(q1f, k1, a, 0, 0, 0);
        if (kb != qb) {
#pragma unroll
          for (int r = 0; r < 4; ++r)
            sm[w][hi4 * 4 + r][ct * 16 + lr] = exp2f(a[r]) * iv[r];
        } else {
          const int colb = kb * 64 + ct * 16 + lr;
#pragma unroll
          for (int r = 0; r < 4; ++r)
            sm[w][hi4 * 4 + r][ct * 16 + lr] =
                (colb <= rowg + r) ? exp2f(a[r]) * iv[r] : 0.f;
        }
      }
      asm volatile("s_waitcnt lgkmcnt(0)" ::: "memory");
#pragma unroll
      for (int j = 0; j < 4; ++j) {
        const int row16 = hi4 + 4 * j;
        const f32x4 pv4 = *(const f32x4*)&sm[w][row16][lr * 4];
        __builtin_nontemporal_store(
            pv4, (f32x4*)&attw[(size_t)(h * S + q0 + w * 16 + row16) * S + kb * 64 + lr * 4]);
      }
#pragma unroll
      for (int ks = 0; ks < 2; ++ks) {
        const f32x4 f0 = *(const f32x4*)&sm[w][lr][ks * 32 + lk];
        const f32x4 f1 = *(const f32x4*)&sm[w][lr][ks * 32 + lk + 4];
        f16x8 pa;
        pa[0] = (_Float16)f0[0]; pa[1] = (_Float16)f0[1];
        pa[2] = (_Float16)f0[2]; pa[3] = (_Float16)f0[3];
        pa[4] = (_Float16)f1[0]; pa[5] = (_Float16)f1[1];
        pa[6] = (_Float16)f1[2]; pa[7] = (_Float16)f1[3];
        const int vbase = (h * 64 + kb) * 4096 + ks * 512 + l * 8;
#pragma unroll
        for (int ct2 = 0; ct2 < 4; ++ct2) {
          f16x8 bv = *(const f16x8*)&VF[vbase + ct2 * 1024];
          o[ct2] = __builtin_amdgcn_mfma_f32_16x16x32_f16(pa, bv, o[ct2], 0, 0, 0);
        }
      }
      asm volatile("" ::: "memory");
    } else {
      const f32x4 z = {0.f, 0.f, 0.f, 0.f};
#pragma unroll
      for (int j = 0; j < 4; ++j) {
        __builtin_nontemporal_store(
            z, (f32x4*)&attw[(size_t)(h * S + q0 + w * 16 + hi4 + 4 * j) * S + kb * 64 + lr * 4]);
      }
    }
  }

#pragma unroll
  for (int ct2 = 0; ct2 < 4; ++ct2)
#pragma unroll
    for (int r = 0; r < 4; ++r)
      ppv[((size_t)(h * NG + gx) * S + rowg + r) * 64 + ct2 * 16 + lr] = f2h(o[ct2][r]);
}

// reduce PV partials (fp16) over groups -> AO in A-fragment order (fp16)
__global__ void pvred_kernel(const u16* __restrict__ ppv, u16* __restrict__ AOF) {
  int t = blockIdx.x * blockDim.x + threadIdx.x;  // S*E/8 threads
  int r = t >> 6, c8 = t & 63;
  int c = c8 * 8;
  int h = c >> 6, dd = c & 63;
  int ng = (r >> 9) + 1;
  float s[8] = {0.f, 0.f, 0.f, 0.f, 0.f, 0.f, 0.f, 0.f};
  for (int g = 0; g < ng; ++g) {
    const f16x8 v = *(const f16x8*)&ppv[((size_t)(h * NG + g) * S + r) * 64 + dd];
#pragma unroll
    for (int j = 0; j < 8; ++j) s[j] += (float)v[j];
  }
  f16x8 o;
#pragma unroll
  for (int j = 0; j < 8; ++j) o[j] = (_Float16)s[j];
  int mb = r >> 6, w = (r >> 4) & 3, ll = r & 15;
  int ks = c >> 5, lhi = (c >> 3) & 3;
  int l = lhi * 16 + ll;
  *(f16x8*)&AOF[(size_t)(((mb * 4 + w) * 16 + ks)) * 512 + l * 8] = o;
}

// final O projection: fragment-order A,B -> fp32 row-major out
__global__ __launch_bounds__(256) void gemm_o_kernel(
    const u16* __restrict__ AF, const u16* __restrict__ BF,
    const float* __restrict__ bias, float* __restrict__ outf) {
  const int mb = blockIdx.x, nb = blockIdx.y;
  const int w = threadIdx.x >> 6, l = threadIdx.x & 63;
  const int lr = l & 15, hi4 = l >> 4;

  f32x4 acc[4] = {{0.f,0.f,0.f,0.f},{0.f,0.f,0.f,0.f},{0.f,0.f,0.f,0.f},{0.f,0.f,0.f,0.f}};
  const u16* abase = AF + (size_t)((mb * 4 + w) * 16) * 512 + l * 8;
  const u16* bbase = BF + (size_t)(nb * 64) * 512 + l * 8;
#pragma unroll
  for (int ks = 0; ks < 16; ++ks) {
    f16x8 ah = *(const f16x8*)(abase + ks * 512);
#pragma unroll
    for (int ct = 0; ct < 4; ++ct) {
      f16x8 bh = *(const f16x8*)(bbase + (ct * 16 + ks) * 512);
      acc[ct] = __builtin_amdgcn_mfma_f32_16x16x32_f16(ah, bh, acc[ct], 0, 0, 0);
    }
  }
  const int rb = mb * 64 + w * 16 + hi4 * 4;
#pragma unroll
  for (int ct = 0; ct < 4; ++ct) {
    int n = nb * 64 + ct * 16 + lr;
    float bia = bias[n];
#pragma unroll
    for (int r = 0; r < 4; ++r)
      outf[(rb + r) * E + n] = acc[ct][r] + bia;
  }
}

extern "C" void kernel_launch(void* const* d_in, const int* in_sizes, int n_in,
                              void* d_out, int out_size, void* d_ws, size_t ws_size,
                              hipStream_t stream) {
  const float* x  = (const float*)d_in[0];
  const float* Wq = (const float*)d_in[2];
  const float* bq = (const float*)d_in[3];
  const float* Wk = (const float*)d_in[4];
  const float* bk = (const float*)d_in[5];
  const float* Wv = (const float*)d_in[6];
  const float* bv = (const float*)d_in[7];
  const float* Wo = (const float*)d_in[8];
  const float* bo = (const float*)d_in[9];

  u16* p = (u16*)d_ws;
  u16* XF  = p; p += S * E;
  u16* wqF = p; p += 512 * 512;
  u16* wkF = p; p += 512 * 512;
  u16* wvF = p; p += 512 * 512;
  u16* woF = p; p += 512 * 512;
  u16* QF  = p; p += S * E;
  u16* KF  = p; p += S * E;
  u16* VF  = p; p += S * E;
  u16* AOF = p; p += S * E;
  size_t ofs = ((size_t)((char*)p - (char*)d_ws) + 15) & ~(size_t)15;
  float* ws_l = (float*)((char*)d_ws + ofs);               // NH*NG*S
  u16*   ppv  = (u16*)(ws_l + (size_t)NH * NG * S);        // NH*NG*S*64 fp16
  char* wend = (char*)(ppv + (size_t)NH * NG * S * 64);

  size_t needed = (size_t)(wend - (char*)d_ws);
  if (ws_size < needed) return;

  float* out  = (float*)d_out;
  float* attw = out + (size_t)S * E;

  xfrag_kernel<<<(S * E / 8) / 256, 256, 0, stream>>>(x, XF);
  wfrag_kernel<<<dim3((512 * 512 / 8) / 256, 4), 256, 0, stream>>>(
      Wq, Wk, Wv, Wo, wqF, wkF, wvF, woF);

  qkv_kernel<<<dim3(S / 64, E / 64, 3), 256, 0, stream>>>(
      XF, wqF, wkF, wvF, bq, bk, bv, QF, KF, VF);

  ksum_kernel<<<dim3(NG, NH, S / 64), 256, 0, stream>>>(QF, KF, ws_l);
  kwts_kernel<<<dim3(NG, NH, S / 64), 256, 0, stream>>>(QF, KF, VF, ws_l, attw, ppv);
  pvred_kernel<<<(S * E / 8) / 256, 256, 0, stream>>>(ppv, AOF);

  gemm_o_kernel<<<dim3(S / 64, E / 64), 256, 0, stream>>>(AOF, woF, bo, out);
}